// Round 13
// baseline (59.444 us; speedup 1.0000x reference)
//
#include <hip/hip_runtime.h>
#include <hip/hip_fp16.h>
#include <math.h>

#define B_ 4
#define Q_ 1024
#define K_ 1024
#define DIN_ 256
#define H_ 64
#define DV_ 128
#define KT 64
#define GQ 4                          // queries per wave
#define MASKP -1000000.0f             // mask in log2 domain -> exp2 = 0
#define C2LOG2E 2.8853900817779268f   // 2*log2(e)
#define LOG2E 1.4426950408889634f
#define S21 4.76837158203125e-7f      // 2^-21 rescale for 4-way rcp batching

typedef float v2f __attribute__((ext_vector_type(2)));

__device__ __forceinline__ float fexp2(float x) {
#if __has_builtin(__builtin_amdgcn_exp2f)
  return __builtin_amdgcn_exp2f(x);
#else
  return exp2f(x);
#endif
}
__device__ __forceinline__ float frcp(float x) {
#if __has_builtin(__builtin_amdgcn_rcpf)
  return __builtin_amdgcn_rcpf(x);
#else
  return 1.0f / x;
#endif
}

// blocks [0,512): row projections; EQ = exp2(C*(q.Wq)) * 2^-21 (prescaled
// for 4-way rcp batching), EK = exp2(C*(k.Wk)) unscaled.
// blocks [512,1024): values -> fp16 (packed pairs)
__global__ __launch_bounds__(256, 4) void prep_kernel(
    const float* __restrict__ queries, const float* __restrict__ keys,
    const float* __restrict__ values,
    const float* __restrict__ Wq, const float* __restrict__ Wk,
    float* __restrict__ eq, float* __restrict__ ek,
    unsigned short* __restrict__ vh) {
  int bid = blockIdx.x;
  int t = threadIdx.x;
  if (bid >= 512) {
    int i = ((bid - 512) * 256 + t) * 4;     // 512*256*4 = B*K*DV
    float4 v = *(const float4*)&values[i];
    ushort4 o;
    o.x = __half_as_ushort(__float2half(v.x));
    o.y = __half_as_ushort(__float2half(v.y));
    o.z = __half_as_ushort(__float2half(v.z));
    o.w = __half_as_ushort(__float2half(v.w));
    *(ushort4*)&vh[i] = o;
    return;
  }
  int w = t >> 6, lane = t & 63;
  int r0 = __builtin_amdgcn_readfirstlane(bid * 16 + w * 4);  // rows r0..r0+3
  const float* src;
  const float* W;
  float* dst;
  float escale;
  if (r0 < B_ * Q_) {
    src = queries + r0 * DIN_; W = Wq; dst = eq + r0 * H_; escale = S21;
  } else {
    int kr = r0 - B_ * Q_;
    src = keys + kr * DIN_; W = Wk; dst = ek + kr * H_; escale = 1.0f;
  }
  float a00 = 0.f, a01 = 0.f, a10 = 0.f, a11 = 0.f;
  float a20 = 0.f, a21 = 0.f, a30 = 0.f, a31 = 0.f;
#pragma unroll 8
  for (int d = 0; d < DIN_; d += 2) {
    float w0 = W[d * H_ + lane];
    float w1 = W[(d + 1) * H_ + lane];
    a00 = fmaf(w0, src[d], a00);             a01 = fmaf(w1, src[d + 1], a01);
    a10 = fmaf(w0, src[DIN_ + d], a10);      a11 = fmaf(w1, src[DIN_ + d + 1], a11);
    a20 = fmaf(w0, src[2 * DIN_ + d], a20);  a21 = fmaf(w1, src[2 * DIN_ + d + 1], a21);
    a30 = fmaf(w0, src[3 * DIN_ + d], a30);  a31 = fmaf(w1, src[3 * DIN_ + d + 1], a31);
  }
  dst[lane]          = fexp2((a00 + a01) * C2LOG2E) * escale;
  dst[H_ + lane]     = fexp2((a10 + a11) * C2LOG2E) * escale;
  dst[2 * H_ + lane] = fexp2((a20 + a21) * C2LOG2E) * escale;
  dst[3 * H_ + lane] = fexp2((a30 + a31) * C2LOG2E) * escale;
}

// Flash attention over ONE K-split span, no max-tracking. Wave owns GQ=4
// queries (16/block) -> 2x compute per staged tile vs GQ=2; lane owns 1 key.
// All in-loop operands LDS-resident. 4-way rcp batching in 2^-21 domain.
__global__ __launch_bounds__(256, 3) void attn_kernel(
    const float* __restrict__ eq, const float* __restrict__ ek,
    const unsigned* __restrict__ vh32, const float* __restrict__ wv,
    const int* __restrict__ vlen,
    float* __restrict__ pl, float* __restrict__ po,
    int ns, int span) {
  __shared__ __align__(16) float ek_s[KT][H_ + 4];     // pad 4: b128-clean
  __shared__ __align__(16) unsigned v_s[KT][DV_ / 2];  // fp16 pairs
  __shared__ __align__(16) float p_s[4][GQ][KT];
  __shared__ float4 eq4_s[16 * 16];                    // 16 q/block (S21)
  __shared__ float4 wv4_s[16];                         // wv * 2^-21
  int t = threadIdx.x;
  int lane = t & 63;
  int w = t >> 6;
  int b = blockIdx.x >> 6;                    // 64 q-blocks (16 q) per batch
  int qt = blockIdx.x & 63;
  int s = blockIdx.y;
  int q0 = __builtin_amdgcn_readfirstlane(qt * 16 + w * GQ);
  int kv = vlen[b];
  int g = b * Q_ + q0;                        // queries g..g+3
  int k_lo = s * span;

  if (k_lo >= kv) {                           // inactive split: l=0 marker
    if (lane == 0) {
#pragma unroll
      for (int i = 0; i < GQ; ++i) pl[(g + i) * ns + s] = 0.f;
    }
    return;
  }

  const float* ekb = ek + (size_t)b * K_ * H_;
  const unsigned* vgb = vh32 + (size_t)b * K_ * (DV_ / 2);

  // stage eq (block's 16 query rows, prescaled) and wv*2^-21 into LDS
  eq4_s[t] = ((const float4*)(eq + (size_t)(b * Q_ + qt * 16) * H_))[t];
  if (t < 16) {
    float4 wq = ((const float4*)wv)[t];
    wq.x *= S21; wq.y *= S21; wq.z *= S21; wq.w *= S21;
    wv4_s[t] = wq;
  }

  // wsum = sum of raw w_v (butterfly)
  float wsum = wv[lane];
#pragma unroll
  for (int sh = 32; sh >= 1; sh >>= 1) wsum += __shfl_xor(wsum, sh);
  float wl2 = wsum * LOG2E;
  const float nl2 = -2.0f * LOG2E;

  float l0 = 0.f, l1 = 0.f, l2 = 0.f, l3 = 0.f;
  v2f o0 = {0.f, 0.f}, o1 = {0.f, 0.f}, o2 = {0.f, 0.f}, o3 = {0.f, 0.f};

  int tile0 = k_lo >> 6;
  int tileE = min((kv + KT - 1) >> 6, (k_lo + span) >> 6);
  const float4* e4a = &eq4_s[(w * GQ + 0) * 16];
  const float4* e4b = &eq4_s[(w * GQ + 1) * 16];
  const float4* e4c = &eq4_s[(w * GQ + 2) * 16];
  const float4* e4d = &eq4_s[(w * GQ + 3) * 16];
  const v2f c2 = {S21, S21};

  for (int tile = tile0; tile < tileE; ++tile) {
    int k0 = tile * KT;
    __syncthreads();                 // prior readers done (+ eq_s visible)
    {
      const float4* gek = (const float4*)(ekb + (size_t)k0 * H_);
      const float4* gv = (const float4*)(vgb + (size_t)k0 * (DV_ / 2));
#pragma unroll
      for (int i = 0; i < 4; ++i) {
        int f4 = i * 256 + t;
        *(float4*)&ek_s[f4 >> 4][(f4 & 15) * 4] = gek[f4];
      }
#pragma unroll
      for (int i = 0; i < 4; ++i) {
        int f4 = i * 256 + t;
        *(float4*)&v_s[f4 >> 4][(f4 & 15) * 4] = gv[f4];
      }
    }
    __syncthreads();

    // scores: 4-way rcp batching in the scaled domain, 4 queries
    float acc0 = 0.f, acc1 = 0.f, acc2 = 0.f, acc3 = 0.f;
#pragma unroll
    for (int h4 = 0; h4 < 16; ++h4) {
      float4 ekq = *(const float4*)&ek_s[lane][h4 * 4];
      float4 wq = wv4_s[h4];
      v2f ek01 = {ekq.x, ekq.y}, ek23 = {ekq.z, ekq.w};
      {
        float4 ea = e4a[h4];
        v2f d01 = __builtin_elementwise_fma((v2f){ea.x, ea.y}, ek01, c2);
        v2f d23 = __builtin_elementwise_fma((v2f){ea.z, ea.w}, ek23, c2);
        float a01 = d01.x * d01.y, a23 = d23.x * d23.y;
        float n01 = fmaf(wq.x, d01.y, wq.y * d01.x);
        float n23 = fmaf(wq.z, d23.y, wq.w * d23.x);
        acc0 = fmaf(fmaf(n01, a23, n23 * a01), frcp(a01 * a23), acc0);
      }
      {
        float4 ea = e4b[h4];
        v2f d01 = __builtin_elementwise_fma((v2f){ea.x, ea.y}, ek01, c2);
        v2f d23 = __builtin_elementwise_fma((v2f){ea.z, ea.w}, ek23, c2);
        float a01 = d01.x * d01.y, a23 = d23.x * d23.y;
        float n01 = fmaf(wq.x, d01.y, wq.y * d01.x);
        float n23 = fmaf(wq.z, d23.y, wq.w * d23.x);
        acc1 = fmaf(fmaf(n01, a23, n23 * a01), frcp(a01 * a23), acc1);
      }
      {
        float4 ea = e4c[h4];
        v2f d01 = __builtin_elementwise_fma((v2f){ea.x, ea.y}, ek01, c2);
        v2f d23 = __builtin_elementwise_fma((v2f){ea.z, ea.w}, ek23, c2);
        float a01 = d01.x * d01.y, a23 = d23.x * d23.y;
        float n01 = fmaf(wq.x, d01.y, wq.y * d01.x);
        float n23 = fmaf(wq.z, d23.y, wq.w * d23.x);
        acc2 = fmaf(fmaf(n01, a23, n23 * a01), frcp(a01 * a23), acc2);
      }
      {
        float4 ea = e4d[h4];
        v2f d01 = __builtin_elementwise_fma((v2f){ea.x, ea.y}, ek01, c2);
        v2f d23 = __builtin_elementwise_fma((v2f){ea.z, ea.w}, ek23, c2);
        float a01 = d01.x * d01.y, a23 = d23.x * d23.y;
        float n01 = fmaf(wq.x, d01.y, wq.y * d01.x);
        float n23 = fmaf(wq.z, d23.y, wq.w * d23.x);
        acc3 = fmaf(fmaf(n01, a23, n23 * a01), frcp(a01 * a23), acc3);
      }
    }
    // p = exp2(LOG2E*score); masked -> exp2(-1e6) = 0
    bool maskd = (k0 + lane) >= kv;
    float t0 = fmaf(nl2, acc0, wl2);
    float t1 = fmaf(nl2, acc1, wl2);
    float t2 = fmaf(nl2, acc2, wl2);
    float t3 = fmaf(nl2, acc3, wl2);
    if (maskd) { t0 = MASKP; t1 = MASKP; t2 = MASKP; t3 = MASKP; }
    float p0 = fexp2(t0), p1 = fexp2(t1), p2 = fexp2(t2), p3 = fexp2(t3);
    l0 += p0; l1 += p1; l2 += p2; l3 += p3;
    p_s[w][0][lane] = p0;
    p_s[w][1][lane] = p1;
    p_s[w][2][lane] = p2;
    p_s[w][3][lane] = p3;            // same-wave write->read, no barrier

    // PV: p broadcast (uniform addr), V fp16 pairs from LDS; float2 math
#pragma unroll 8
    for (int k4 = 0; k4 < KT / 4; ++k4) {
      int kk = k4 * 4;
      float4 P0 = *(const float4*)&p_s[w][0][kk];
      float4 P1 = *(const float4*)&p_s[w][1][kk];
      float4 P2 = *(const float4*)&p_s[w][2][kk];
      float4 P3 = *(const float4*)&p_s[w][3][kk];
      unsigned u0 = v_s[kk][lane];
      unsigned u1 = v_s[kk + 1][lane];
      unsigned u2 = v_s[kk + 2][lane];
      unsigned u3 = v_s[kk + 3][lane];
      __half2 h0 = *(__half2*)&u0, h1 = *(__half2*)&u1;
      __half2 h2 = *(__half2*)&u2, h3 = *(__half2*)&u3;
      v2f v0 = {__low2float(h0), __high2float(h0)};
      v2f v1 = {__low2float(h1), __high2float(h1)};
      v2f v2 = {__low2float(h2), __high2float(h2)};
      v2f v3 = {__low2float(h3), __high2float(h3)};
      o0 = __builtin_elementwise_fma((v2f){P0.x, P0.x}, v0, o0);
      o1 = __builtin_elementwise_fma((v2f){P1.x, P1.x}, v0, o1);
      o2 = __builtin_elementwise_fma((v2f){P2.x, P2.x}, v0, o2);
      o3 = __builtin_elementwise_fma((v2f){P3.x, P3.x}, v0, o3);
      o0 = __builtin_elementwise_fma((v2f){P0.y, P0.y}, v1, o0);
      o1 = __builtin_elementwise_fma((v2f){P1.y, P1.y}, v1, o1);
      o2 = __builtin_elementwise_fma((v2f){P2.y, P2.y}, v1, o2);
      o3 = __builtin_elementwise_fma((v2f){P3.y, P3.y}, v1, o3);
      o0 = __builtin_elementwise_fma((v2f){P0.z, P0.z}, v2, o0);
      o1 = __builtin_elementwise_fma((v2f){P1.z, P1.z}, v2, o1);
      o2 = __builtin_elementwise_fma((v2f){P2.z, P2.z}, v2, o2);
      o3 = __builtin_elementwise_fma((v2f){P3.z, P3.z}, v2, o3);
      o0 = __builtin_elementwise_fma((v2f){P0.w, P0.w}, v3, o0);
      o1 = __builtin_elementwise_fma((v2f){P1.w, P1.w}, v3, o1);
      o2 = __builtin_elementwise_fma((v2f){P2.w, P2.w}, v3, o2);
      o3 = __builtin_elementwise_fma((v2f){P3.w, P3.w}, v3, o3);
    }
  }

  // l: one reduce per split (not per tile)
#pragma unroll
  for (int sh = 32; sh >= 1; sh >>= 1) {
    l0 += __shfl_xor(l0, sh);
    l1 += __shfl_xor(l1, sh);
    l2 += __shfl_xor(l2, sh);
    l3 += __shfl_xor(l3, sh);
  }
  if (lane == 0) {
    pl[(g + 0) * ns + s] = l0;
    pl[(g + 1) * ns + s] = l1;
    pl[(g + 2) * ns + s] = l2;
    pl[(g + 3) * ns + s] = l3;
  }
  size_t pb = ((size_t)g * ns + s) * DV_ + lane * 2;
  *(float2*)&po[pb] = make_float2(o0.x, o0.y);
  *(float2*)&po[pb + (size_t)ns * DV_] = make_float2(o1.x, o1.y);
  *(float2*)&po[pb + (size_t)2 * ns * DV_] = make_float2(o2.x, o2.y);
  *(float2*)&po[pb + (size_t)3 * ns * DV_] = make_float2(o3.x, o3.y);
}

// out = (sum_s o_s) / (sum_s l_s); skip l==0 splits (po unwritten there)
__global__ __launch_bounds__(256, 4) void combine_kernel(
    const float* __restrict__ pl, const float* __restrict__ po,
    float* __restrict__ out, int ns) {
  int t = threadIdx.x;
  int lane = t & 63;
  int w = t >> 6;
  int g = blockIdx.x * 4 + w;
  float L = 0.f, ax = 0.f, ay = 0.f;
  for (int s = 0; s < ns; ++s) {
    float ls = pl[g * ns + s];
    if (ls != 0.f) {                 // wave-uniform
      L += ls;
      float2 o2 = *(const float2*)&po[((size_t)g * ns + s) * DV_ + lane * 2];
      ax += o2.x;
      ay += o2.y;
    }
  }
  float inv = frcp(L);
  *(float2*)&out[(size_t)g * DV_ + lane * 2] = make_float2(ax * inv, ay * inv);
}

extern "C" void kernel_launch(void* const* d_in, const int* in_sizes, int n_in,
                              void* d_out, int out_size, void* d_ws, size_t ws_size,
                              hipStream_t stream) {
  const float* queries = (const float*)d_in[0];
  const float* keys    = (const float*)d_in[1];
  const float* values  = (const float*)d_in[2];
  const int*   vl      = (const int*)d_in[3];
  const float* Wq      = (const float*)d_in[4];
  const float* Wk      = (const float*)d_in[5];
  const float* wv      = (const float*)d_in[6];
  float* out = (float*)d_out;

  float* eq = (float*)d_ws;                              // 1 MB
  float* ek = eq + (size_t)B_ * Q_ * H_;                 // 1 MB
  unsigned short* vh = (unsigned short*)(ek + (size_t)B_ * K_ * H_);  // 1 MB
  char* dyn = (char*)(vh + (size_t)B_ * K_ * DV_);
  size_t fixed = (size_t)(dyn - (char*)d_ws);

  // choose K-split count by available workspace (deterministic per session)
  int ns = 2;
  for (int cand = 8; cand >= 2; cand >>= 1) {
    size_t need = fixed + (size_t)B_ * Q_ * cand * 4            // pl
                + (size_t)B_ * Q_ * cand * DV_ * 4;             // po
    if (ws_size >= need) { ns = cand; break; }
  }
  int span = K_ / ns;
  float* pl = (float*)dyn;
  float* po = pl + (size_t)B_ * Q_ * ns;

  prep_kernel<<<dim3(1024), dim3(256), 0, stream>>>(
      queries, keys, values, Wq, Wk, eq, ek, vh);
  attn_kernel<<<dim3(B_ * (Q_ / 16), ns), dim3(256), 0, stream>>>(
      eq, ek, (const unsigned*)vh, wv, vl, pl, po, ns, span);
  combine_kernel<<<dim3(B_ * Q_ / 4), dim3(256), 0, stream>>>(pl, po, out, ns);
}

// Round 14
// 38.710 us; speedup vs baseline: 1.5356x; 1.5356x over previous
//
#include <hip/hip_runtime.h>
#include <hip/hip_fp16.h>
#include <math.h>

#define B_ 4
#define Q_ 1024
#define K_ 1024
#define DIN_ 256
#define H_ 64
#define DV_ 128
#define KT 64
#define MASKP -1000000.0f    // mask in log2 domain -> exp2 = 0
#define C2LOG2E 2.8853900817779268f   // 2*log2(e)
#define LOG2E 1.4426950408889634f
#define EKMAX 60000.0f       // fp16-safe clamp; tanh error <= 3e-5

__device__ __forceinline__ float fexp2(float x) {
#if __has_builtin(__builtin_amdgcn_exp2f)
  return __builtin_amdgcn_exp2f(x);
#else
  return exp2f(x);
#endif
}
__device__ __forceinline__ float frcp(float x) {
#if __has_builtin(__builtin_amdgcn_rcpf)
  return __builtin_amdgcn_rcpf(x);
#else
  return 1.0f / x;
#endif
}

// blocks [0,512): row projections; EQ = exp2(C*(q.Wq)) fp32,
//                 EK = min(exp2(C*(k.Wk)), 60000) as fp16.
// blocks [512,1024): values -> fp16 (packed pairs)
__global__ __launch_bounds__(256, 4) void prep_kernel(
    const float* __restrict__ queries, const float* __restrict__ keys,
    const float* __restrict__ values,
    const float* __restrict__ Wq, const float* __restrict__ Wk,
    float* __restrict__ eq, unsigned short* __restrict__ ekh,
    unsigned short* __restrict__ vh) {
  int bid = blockIdx.x;
  int t = threadIdx.x;
  if (bid >= 512) {
    int i = ((bid - 512) * 256 + t) * 4;     // 512*256*4 = B*K*DV
    float4 v = *(const float4*)&values[i];
    ushort4 o;
    o.x = __half_as_ushort(__float2half(v.x));
    o.y = __half_as_ushort(__float2half(v.y));
    o.z = __half_as_ushort(__float2half(v.z));
    o.w = __half_as_ushort(__float2half(v.w));
    *(ushort4*)&vh[i] = o;
    return;
  }
  int w = t >> 6, lane = t & 63;
  int r0 = __builtin_amdgcn_readfirstlane(bid * 16 + w * 4);  // rows r0..r0+3
  bool isq = (r0 < B_ * Q_);
  const float* src;
  const float* W;
  if (isq) { src = queries + r0 * DIN_; W = Wq; }
  else     { src = keys + (r0 - B_ * Q_) * DIN_; W = Wk; }
  float a00 = 0.f, a01 = 0.f, a10 = 0.f, a11 = 0.f;
  float a20 = 0.f, a21 = 0.f, a30 = 0.f, a31 = 0.f;
#pragma unroll 8
  for (int d = 0; d < DIN_; d += 2) {
    float w0 = W[d * H_ + lane];
    float w1 = W[(d + 1) * H_ + lane];
    a00 = fmaf(w0, src[d], a00);             a01 = fmaf(w1, src[d + 1], a01);
    a10 = fmaf(w0, src[DIN_ + d], a10);      a11 = fmaf(w1, src[DIN_ + d + 1], a11);
    a20 = fmaf(w0, src[2 * DIN_ + d], a20);  a21 = fmaf(w1, src[2 * DIN_ + d + 1], a21);
    a30 = fmaf(w0, src[3 * DIN_ + d], a30);  a31 = fmaf(w1, src[3 * DIN_ + d + 1], a31);
  }
  float e0 = fexp2((a00 + a01) * C2LOG2E);
  float e1 = fexp2((a10 + a11) * C2LOG2E);
  float e2 = fexp2((a20 + a21) * C2LOG2E);
  float e3 = fexp2((a30 + a31) * C2LOG2E);
  if (isq) {
    float* dst = eq + r0 * H_;
    dst[lane] = e0; dst[H_ + lane] = e1;
    dst[2 * H_ + lane] = e2; dst[3 * H_ + lane] = e3;
  } else {
    unsigned short* dst = ekh + (r0 - B_ * Q_) * H_;
    dst[lane]          = __half_as_ushort(__float2half(fminf(e0, EKMAX)));
    dst[H_ + lane]     = __half_as_ushort(__float2half(fminf(e1, EKMAX)));
    dst[2 * H_ + lane] = __half_as_ushort(__float2half(fminf(e2, EKMAX)));
    dst[3 * H_ + lane] = __half_as_ushort(__float2half(fminf(e3, EKMAX)));
  }
}

// Flash attention over ONE K-split span, no max-tracking. Wave owns 2
// queries; lane owns 1 key. All in-loop operands LDS-resident. EK fp16:
// half the staging + DS-read volume of R10; [KT][34]-unsigned layout ->
// ds_read_b64 at bank (2*lane+off)%32 = 2-way (free). 29.4 KB LDS ->
// 5 blocks/CU.
__global__ __launch_bounds__(256, 5) void attn_kernel(
    const float* __restrict__ eq, const unsigned short* __restrict__ ekh,
    const unsigned* __restrict__ vh32, const float* __restrict__ wv,
    const int* __restrict__ vlen,
    float* __restrict__ pl, float* __restrict__ po,
    int ns, int span) {
  __shared__ __align__(16) unsigned ek_s[KT][H_ / 2 + 2];  // fp16 pairs
  __shared__ __align__(16) unsigned v_s[KT][DV_ / 2];      // fp16 pairs
  __shared__ __align__(16) float p_s[4][2][KT];
  __shared__ float4 eq4_s[8 * 16];                         // [q][h4]
  __shared__ float4 wv4_s[16];
  int t = threadIdx.x;
  int lane = t & 63;
  int w = t >> 6;
  int b = blockIdx.x >> 7;                    // 128 q-blocks (8 q) per batch
  int qt = blockIdx.x & 127;
  int s = blockIdx.y;
  int q0 = __builtin_amdgcn_readfirstlane(qt * 8 + w * 2);
  int kv = vlen[b];
  int g = b * Q_ + q0;                        // queries g, g+1
  int k_lo = s * span;

  if (k_lo >= kv) {                           // inactive split: l=0 marker
    if (lane == 0) {
      pl[(g + 0) * ns + s] = 0.f;
      pl[(g + 1) * ns + s] = 0.f;
    }
    return;
  }

  const unsigned short* ekb = ekh + (size_t)b * K_ * H_;
  const unsigned* vgb = vh32 + (size_t)b * K_ * (DV_ / 2);

  // stage eq (block's 8 query rows) and wv into LDS
  if (t < 128)
    eq4_s[t] = ((const float4*)(eq + (size_t)(b * Q_ + qt * 8) * H_))[t];
  if (t < 16) wv4_s[t] = ((const float4*)wv)[t];

  // wsum = sum of w_v (butterfly)
  float wsum = wv[lane];
#pragma unroll
  for (int sh = 32; sh >= 1; sh >>= 1) wsum += __shfl_xor(wsum, sh);
  float wl2 = wsum * LOG2E;
  const float nl2 = -2.0f * LOG2E;

  float l0 = 0.f, l1 = 0.f;
  float o0x = 0.f, o0y = 0.f, o1x = 0.f, o1y = 0.f;

  int tile0 = k_lo >> 6;
  int tileE = min((kv + KT - 1) >> 6, (k_lo + span) >> 6);
  const float4* e4a = &eq4_s[(w * 2 + 0) * 16];
  const float4* e4b = &eq4_s[(w * 2 + 1) * 16];

  for (int tile = tile0; tile < tileE; ++tile) {
    int k0 = tile * KT;
    __syncthreads();                 // prior readers done (+ eq_s visible)
    {
      // ek tile: 64 rows x 64 fp16 = 8 KB = 512 float4; 2 per thread
      const float4* gek = (const float4*)(ekb + (size_t)k0 * H_);
#pragma unroll
      for (int i = 0; i < 2; ++i) {
        int f4 = i * 256 + t;
        float4 v = gek[f4];
        int r = f4 >> 3, c = (f4 & 7) * 4;
        *(float2*)&ek_s[r][c] = make_float2(v.x, v.y);
        *(float2*)&ek_s[r][c + 2] = make_float2(v.z, v.w);
      }
      // v tile: 64 rows x 64 fp16-pairs = 16 KB = 1024 float4; 4 per thread
      const float4* gv = (const float4*)(vgb + (size_t)k0 * (DV_ / 2));
#pragma unroll
      for (int i = 0; i < 4; ++i) {
        int f4 = i * 256 + t;
        *(float4*)&v_s[f4 >> 4][(f4 & 15) * 4] = gv[f4];
      }
    }
    __syncthreads();

    // scores, paired-h: w0/d0 + w1/d1 = (w0*d1 + w1*d0) / (d0*d1)
    const unsigned* ekrow = ek_s[lane];
    float acc0 = 0.f, acc1 = 0.f;
#pragma unroll
    for (int h8 = 0; h8 < 8; ++h8) {
      uint2 eu0 = *(const uint2*)&ekrow[h8 * 4];
      uint2 eu1 = *(const uint2*)&ekrow[h8 * 4 + 2];
      __half2 eh0 = *(__half2*)&eu0.x, eh1 = *(__half2*)&eu0.y;
      __half2 eh2 = *(__half2*)&eu1.x, eh3 = *(__half2*)&eu1.y;
      float k0f = __low2float(eh0), k1f = __high2float(eh0);
      float k2f = __low2float(eh1), k3f = __high2float(eh1);
      float k4f = __low2float(eh2), k5f = __high2float(eh2);
      float k6f = __low2float(eh3), k7f = __high2float(eh3);
      float4 wqA = wv4_s[h8 * 2], wqB = wv4_s[h8 * 2 + 1];
      float4 eaA = e4a[h8 * 2], eaB = e4a[h8 * 2 + 1];
      float4 ebA = e4b[h8 * 2], ebB = e4b[h8 * 2 + 1];
      {
        float d0 = fmaf(eaA.x, k0f, 1.f), d1 = fmaf(eaA.y, k1f, 1.f);
        acc0 = fmaf(fmaf(wqA.y, d0, wqA.x * d1), frcp(d0 * d1), acc0);
        float d2 = fmaf(eaA.z, k2f, 1.f), d3 = fmaf(eaA.w, k3f, 1.f);
        acc0 = fmaf(fmaf(wqA.w, d2, wqA.z * d3), frcp(d2 * d3), acc0);
        float d4 = fmaf(eaB.x, k4f, 1.f), d5 = fmaf(eaB.y, k5f, 1.f);
        acc0 = fmaf(fmaf(wqB.y, d4, wqB.x * d5), frcp(d4 * d5), acc0);
        float d6 = fmaf(eaB.z, k6f, 1.f), d7 = fmaf(eaB.w, k7f, 1.f);
        acc0 = fmaf(fmaf(wqB.w, d6, wqB.z * d7), frcp(d6 * d7), acc0);
      }
      {
        float d0 = fmaf(ebA.x, k0f, 1.f), d1 = fmaf(ebA.y, k1f, 1.f);
        acc1 = fmaf(fmaf(wqA.y, d0, wqA.x * d1), frcp(d0 * d1), acc1);
        float d2 = fmaf(ebA.z, k2f, 1.f), d3 = fmaf(ebA.w, k3f, 1.f);
        acc1 = fmaf(fmaf(wqA.w, d2, wqA.z * d3), frcp(d2 * d3), acc1);
        float d4 = fmaf(ebB.x, k4f, 1.f), d5 = fmaf(ebB.y, k5f, 1.f);
        acc1 = fmaf(fmaf(wqB.y, d4, wqB.x * d5), frcp(d4 * d5), acc1);
        float d6 = fmaf(ebB.z, k6f, 1.f), d7 = fmaf(ebB.w, k7f, 1.f);
        acc1 = fmaf(fmaf(wqB.w, d6, wqB.z * d7), frcp(d6 * d7), acc1);
      }
    }
    // p = exp2(LOG2E*score); masked -> exp2(-1e6) = 0
    bool maskd = (k0 + lane) >= kv;
    float t0 = fmaf(nl2, acc0, wl2);
    float t1 = fmaf(nl2, acc1, wl2);
    if (maskd) { t0 = MASKP; t1 = MASKP; }
    float p0 = fexp2(t0), p1 = fexp2(t1);
    l0 += p0; l1 += p1;
    p_s[w][0][lane] = p0;
    p_s[w][1][lane] = p1;            // same-wave write->read, no barrier

    // PV: p broadcast (uniform addr), V fp16 pairs per-lane from LDS
#pragma unroll 8
    for (int k4 = 0; k4 < KT / 4; ++k4) {
      int kk = k4 * 4;
      float4 P0 = *(const float4*)&p_s[w][0][kk];
      float4 P1 = *(const float4*)&p_s[w][1][kk];
      unsigned u0 = v_s[kk][lane];
      unsigned u1 = v_s[kk + 1][lane];
      unsigned u2 = v_s[kk + 2][lane];
      unsigned u3 = v_s[kk + 3][lane];
      __half2 h0 = *(__half2*)&u0, h1 = *(__half2*)&u1;
      __half2 h2 = *(__half2*)&u2, h3 = *(__half2*)&u3;
      float v0x = __low2float(h0), v0y = __high2float(h0);
      float v1x = __low2float(h1), v1y = __high2float(h1);
      float v2x = __low2float(h2), v2y = __high2float(h2);
      float v3x = __low2float(h3), v3y = __high2float(h3);
      o0x = fmaf(P0.x, v0x, o0x); o0y = fmaf(P0.x, v0y, o0y);
      o1x = fmaf(P1.x, v0x, o1x); o1y = fmaf(P1.x, v0y, o1y);
      o0x = fmaf(P0.y, v1x, o0x); o0y = fmaf(P0.y, v1y, o0y);
      o1x = fmaf(P1.y, v1x, o1x); o1y = fmaf(P1.y, v1y, o1y);
      o0x = fmaf(P0.z, v2x, o0x); o0y = fmaf(P0.z, v2y, o0y);
      o1x = fmaf(P1.z, v2x, o1x); o1y = fmaf(P1.z, v2y, o1y);
      o0x = fmaf(P0.w, v3x, o0x); o0y = fmaf(P0.w, v3y, o0y);
      o1x = fmaf(P1.w, v3x, o1x); o1y = fmaf(P1.w, v3y, o1y);
    }
  }

  // l: one reduce per split (not per tile)
#pragma unroll
  for (int sh = 32; sh >= 1; sh >>= 1) {
    l0 += __shfl_xor(l0, sh);
    l1 += __shfl_xor(l1, sh);
  }
  if (lane == 0) {
    pl[(g + 0) * ns + s] = l0;
    pl[(g + 1) * ns + s] = l1;
  }
  size_t pb = ((size_t)g * ns + s) * DV_ + lane * 2;
  *(float2*)&po[pb] = make_float2(o0x, o0y);
  *(float2*)&po[pb + (size_t)ns * DV_] = make_float2(o1x, o1y);
}

// out = (sum_s o_s) / (sum_s l_s); skip l==0 splits (po unwritten there)
__global__ __launch_bounds__(256, 4) void combine_kernel(
    const float* __restrict__ pl, const float* __restrict__ po,
    float* __restrict__ out, int ns) {
  int t = threadIdx.x;
  int lane = t & 63;
  int w = t >> 6;
  int g = blockIdx.x * 4 + w;
  float L = 0.f, ax = 0.f, ay = 0.f;
  for (int s = 0; s < ns; ++s) {
    float ls = pl[g * ns + s];
    if (ls != 0.f) {                 // wave-uniform
      L += ls;
      float2 o2 = *(const float2*)&po[((size_t)g * ns + s) * DV_ + lane * 2];
      ax += o2.x;
      ay += o2.y;
    }
  }
  float inv = frcp(L);
  *(float2*)&out[(size_t)g * DV_ + lane * 2] = make_float2(ax * inv, ay * inv);
}

extern "C" void kernel_launch(void* const* d_in, const int* in_sizes, int n_in,
                              void* d_out, int out_size, void* d_ws, size_t ws_size,
                              hipStream_t stream) {
  const float* queries = (const float*)d_in[0];
  const float* keys    = (const float*)d_in[1];
  const float* values  = (const float*)d_in[2];
  const int*   vl      = (const int*)d_in[3];
  const float* Wq      = (const float*)d_in[4];
  const float* Wk      = (const float*)d_in[5];
  const float* wv      = (const float*)d_in[6];
  float* out = (float*)d_out;

  float* eq = (float*)d_ws;                               // 1 MB
  unsigned short* ekh = (unsigned short*)(eq + (size_t)B_ * Q_ * H_);  // 0.5 MB
  unsigned short* vh = ekh + (size_t)B_ * K_ * H_;        // 1 MB
  char* dyn = (char*)(vh + (size_t)B_ * K_ * DV_);
  size_t fixed = (size_t)(dyn - (char*)d_ws);

  // choose K-split count by available workspace (deterministic per session)
  int ns = 2;
  for (int cand = 8; cand >= 2; cand >>= 1) {
    size_t need = fixed + (size_t)B_ * Q_ * cand * 4            // pl
                + (size_t)B_ * Q_ * cand * DV_ * 4;             // po
    if (ws_size >= need) { ns = cand; break; }
  }
  int span = K_ / ns;
  float* pl = (float*)dyn;
  float* po = pl + (size_t)B_ * Q_ * ns;

  prep_kernel<<<dim3(1024), dim3(256), 0, stream>>>(
      queries, keys, values, Wq, Wk, eq, ekh, vh);
  attn_kernel<<<dim3(B_ * (Q_ / 8), ns), dim3(256), 0, stream>>>(
      eq, ekh, (const unsigned*)vh, wv, vl, pl, po, ns, span);
  combine_kernel<<<dim3(B_ * Q_ / 4), dim3(256), 0, stream>>>(pl, po, out, ns);
}